// Round 6
// baseline (184.460 us; speedup 1.0000x reference)
//
#include <hip/hip_runtime.h>
#include <cfloat>

typedef __attribute__((ext_vector_type(8))) short short8;
typedef __attribute__((ext_vector_type(4))) short short4v;
typedef __attribute__((ext_vector_type(4))) float f32x4;

#define NE 1024
#define EDIM 256
#define HW 1024
#define BSTRIDE (EDIM * HW)        // 262144
#define TOTAL 8388608

// workspace layout (bytes)
#define EMBS_OFF  0                        // bf16 B, MFMA-frag-swizzled: 512 KB
#define EMBB_OFF  (512 * 1024)             // bf16 emb row-major: 512 KB
#define ENORM_OFF (1024 * 1024)            // float[1024]
#define HIST_OFF  (ENORM_OFF + 4096)       // int[1024]
#define LOSS_OFF  (HIST_OFF + 4096)        // float lossAcc; int ticket at +4

// round-to-nearest-even fp32 -> bf16 bits (inputs are finite)
__device__ __forceinline__ unsigned short f2bf(float x) {
    unsigned u = __builtin_bit_cast(unsigned, x);
    return (unsigned short)((u + 0x7fffu + ((u >> 16) & 1u)) >> 16);
}
__device__ __forceinline__ float bf2f(unsigned short b) {
    return __builtin_bit_cast(float, (unsigned)b << 16);
}

// ---------------------------------------------------------------------------
// P: emb fp32 -> embS (MFMA-B-frag swizzled) + embB (row-major bf16) + enorm.
// Thread = (row, ks): 32 channels. Also zeroes hist/lossAcc/ticket.
// ---------------------------------------------------------------------------
__global__ void prep_emb(const float* __restrict__ emb,
                         unsigned short* __restrict__ embS,
                         unsigned short* __restrict__ embB,
                         float* __restrict__ enorm,
                         int* __restrict__ hist, float* __restrict__ lossAcc,
                         int* __restrict__ ticket) {
    int gid = blockIdx.x * 256 + threadIdx.x;   // 0..8191
    int row = gid >> 3, ks = gid & 7;
    const float4* e4 = (const float4*)(emb + (size_t)row * EDIM + ks * 32);
    float s = 0.f;
    short8 v[4];
#pragma unroll
    for (int q = 0; q < 4; ++q) {
        float4 a = e4[2 * q], b = e4[2 * q + 1];
        s += a.x * a.x + a.y * a.y + a.z * a.z + a.w * a.w
           + b.x * b.x + b.y * b.y + b.z * b.z + b.w * b.w;
        v[q][0] = (short)f2bf(a.x); v[q][1] = (short)f2bf(a.y);
        v[q][2] = (short)f2bf(a.z); v[q][3] = (short)f2bf(a.w);
        v[q][4] = (short)f2bf(b.x); v[q][5] = (short)f2bf(b.y);
        v[q][6] = (short)f2bf(b.z); v[q][7] = (short)f2bf(b.w);
    }
    short8* oS = (short8*)embS;
    int base = ((row >> 4) * 8 + ks) * 64 + (row & 15);
    short8* oB = (short8*)(embB + (size_t)row * EDIM + ks * 32);
#pragma unroll
    for (int q = 0; q < 4; ++q) { oS[base + q * 16] = v[q]; oB[q] = v[q]; }
    s += __shfl_xor(s, 1, 64);
    s += __shfl_xor(s, 2, 64);
    s += __shfl_xor(s, 4, 64);
    if (ks == 0) enorm[row] = s;
    if (gid < NE) hist[gid] = 0;
    if (gid == NE) { lossAcc[0] = 0.f; ticket[0] = 0; }
}

// ---------------------------------------------------------------------------
// F: fused argmin + gather + z_q + loss + hist + (last block) finalize.
// Block = 64 positions, grid 512, 3 blocks/CU (LDS 43.5 KB, VGPR<=170).
// Wave (mw,nw): 32 positions (A[2][8] register-resident) x 512 codes
// streamed as coalesced 1 KB B-frag loads from L2. No main-loop barriers.
// ---------------------------------------------------------------------------
__global__ __launch_bounds__(256, 3) void fused_kernel(
        const float* __restrict__ z, const short8* __restrict__ embS,
        const unsigned short* __restrict__ embB, const float* __restrict__ enormG,
        float* __restrict__ out, int* __restrict__ hist,
        float* __restrict__ lossAcc, int* __restrict__ ticket) {
    __shared__ __align__(16) unsigned short As[64 * 264];  // z bf16 [p][c]
    __shared__ __align__(16) unsigned short Et[64 * 66];   // emb chunk [c][p]
    __shared__ float rv[2][64];
    __shared__ int   ri[2][64];
    __shared__ int   idxm[64];
    __shared__ float wsum[4];
    __shared__ int   lastFlag;

    int t = threadIdx.x;
    int m0 = blockIdx.x * 64;
    int b = m0 >> 10, pb = m0 & 1023;
    const float* zb = z + (size_t)b * BSTRIDE + pb;
    float*     outb = out + (size_t)b * BSTRIDE + pb;

    {   // stage A: 64 positions x 256 channels, bf16, [p][c]
        int p = t & 63, cg = t >> 6;
        const float* zp = zb + p;
        for (int c8 = 0; c8 < 8; ++c8) {
            short8 v;
#pragma unroll
            for (int j = 0; j < 8; ++j)
                v[j] = (short)f2bf(zp[(size_t)(cg * 64 + c8 * 8 + j) * HW]);
            *(short8*)&As[p * 264 + cg * 64 + c8 * 8] = v;
        }
    }
    __syncthreads();

    int w = t >> 6, l = t & 63, lm = l & 15, q = l >> 4;
    int mw = w >> 1, nw = w & 1;

    short8 A[2][8];                        // 64 VGPR, must stay resident
#pragma unroll
    for (int s = 0; s < 2; ++s)
#pragma unroll
        for (int ks = 0; ks < 8; ++ks)
            A[s][ks] = *(const short8*)&As[(mw * 32 + s * 16 + lm) * 264 + ks * 32 + q * 8];

    float bd[8]; int bi[8];
#pragma unroll
    for (int i = 0; i < 8; ++i) { bd[i] = FLT_MAX; bi[i] = 0x7fffffff; }

    // wave streams its 512-code half: 32 tiles of 16; 1 KB coalesced loads
    const short8* eS = embS + (size_t)(nw * 32) * 512 + l;
    for (int nt = 0; nt < 32; ++nt) {
        const short8* ep = eS + nt * 512;
        f32x4 a0 = {0.f, 0.f, 0.f, 0.f}, a1 = {0.f, 0.f, 0.f, 0.f};
#pragma unroll
        for (int h = 0; h < 2; ++h) {
            short8 Bv[4];
#pragma unroll
            for (int k2 = 0; k2 < 4; ++k2) Bv[k2] = ep[(h * 4 + k2) * 64];
#pragma unroll
            for (int k2 = 0; k2 < 4; ++k2) {
                int ks = h * 4 + k2;
                a0 = __builtin_amdgcn_mfma_f32_16x16x32_bf16(A[0][ks], Bv[k2], a0, 0, 0, 0);
                a1 = __builtin_amdgcn_mfma_f32_16x16x32_bf16(A[1][ks], Bv[k2], a1, 0, 0, 0);
            }
        }
        int code = nw * 512 + nt * 16 + lm;
        float en = enormG[code];
#pragma unroll
        for (int r = 0; r < 4; ++r) {
            float d0 = en - 2.f * a0[r];
            if (d0 < bd[r])     { bd[r] = d0;     bi[r] = code; }
            float d1 = en - 2.f * a1[r];
            if (d1 < bd[4 + r]) { bd[4 + r] = d1; bi[4 + r] = code; }
        }
    }

    // reduce across the 16 code-columns (lanes sharing q)
#pragma unroll
    for (int off = 1; off < 16; off <<= 1) {
#pragma unroll
        for (int i = 0; i < 8; ++i) {
            float od = __shfl_xor(bd[i], off, 64);
            int   oi = __shfl_xor(bi[i], off, 64);
            if (od < bd[i] || (od == bd[i] && oi < bi[i])) { bd[i] = od; bi[i] = oi; }
        }
    }
    if (lm == 0) {
#pragma unroll
        for (int s = 0; s < 2; ++s)
#pragma unroll
            for (int r = 0; r < 4; ++r) {
                int p = mw * 32 + s * 16 + q * 4 + r;   // D row = q*4+r
                rv[nw][p] = bd[s * 4 + r];
                ri[nw][p] = bi[s * 4 + r];
            }
    }
    __syncthreads();
    if (t < 64) {   // merge the 2 nw halves (disjoint ascending code ranges)
        float v0 = rv[0][t]; int i0 = ri[0][t];
        float v1 = rv[1][t]; int i1 = ri[1][t];
        int best = (v1 < v0 || (v1 == v0 && i1 < i0)) ? i1 : i0;
        idxm[t] = best;
        atomicAdd(&hist[best], 1);
    }
    __syncthreads();

    // epilogue: 4 chunks of 64 channels; z_q from bf16 embB, loss vs bf16 As
    float ls = 0.f;
    int r = t >> 2, qo = t & 3;            // gather: position r, 16-ch quarter
    int pq = t & 15, cw = t >> 4;          // write: 4 pos x 4 ch per thread
    for (int g = 0; g < 4; ++g) {
        {   // stage Et[c_local][p] bf16 for this 64-ch chunk
            const short8* er = (const short8*)(embB + (size_t)idxm[r] * EDIM + g * 64 + qo * 16);
            short8 v0 = er[0], v1 = er[1];
#pragma unroll
            for (int u = 0; u < 8; ++u) {
                Et[(qo * 16 + u) * 66 + r]     = (unsigned short)v0[u];
                Et[(qo * 16 + 8 + u) * 66 + r] = (unsigned short)v1[u];
            }
        }
        __syncthreads();
#pragma unroll
        for (int cc = 0; cc < 4; ++cc) {
            int cl = cw * 4 + cc;          // channel within chunk
            int c = g * 64 + cl;
            short4v ev4 = *(const short4v*)&Et[cl * 66 + pq * 4];
            f32x4 ev;
            ev[0] = bf2f((unsigned short)ev4[0]); ev[1] = bf2f((unsigned short)ev4[1]);
            ev[2] = bf2f((unsigned short)ev4[2]); ev[3] = bf2f((unsigned short)ev4[3]);
            __builtin_nontemporal_store(ev, (f32x4*)&outb[(size_t)c * HW + pq * 4]);
#pragma unroll
            for (int pi = 0; pi < 4; ++pi) {
                float zv = bf2f(As[(pq * 4 + pi) * 264 + c]);
                float d = ev[pi] - zv;
                ls += d * d;
            }
        }
        __syncthreads();   // Et consumed before next chunk overwrites
    }
#pragma unroll
    for (int off = 32; off; off >>= 1) ls += __shfl_down(ls, off, 64);
    if ((t & 63) == 0) atomicAdd(lossAcc, ls);

    // ---- last-block finalize (device-scope ticket) ----
    __threadfence();
    __syncthreads();
    if (t == 0) lastFlag = (atomicAdd(ticket, 1) == 511);
    __syncthreads();
    if (lastFlag) {
        __threadfence();
        float s = 0.f;
        for (int j = t; j < NE; j += 256) {
            float p = (float)atomicAdd(&hist[j], 0) * (1.0f / 32768.0f);
            s += p * logf(p + 1e-10f);
        }
#pragma unroll
        for (int off = 32; off; off >>= 1) s += __shfl_down(s, off, 64);
        if ((t & 63) == 0) wsum[t >> 6] = s;
        __syncthreads();
        if (t == 0) {
            float S = wsum[0] + wsum[1] + wsum[2] + wsum[3];
            float L = atomicAdd(lossAcc, 0.0f);
            out[TOTAL]     = 1.25f * L / (float)TOTAL;
            out[TOTAL + 1] = expf(-S);
        }
    }
}

extern "C" void kernel_launch(void* const* d_in, const int* in_sizes, int n_in,
                              void* d_out, int out_size, void* d_ws, size_t ws_size,
                              hipStream_t stream) {
    (void)in_sizes; (void)n_in; (void)out_size; (void)ws_size;
    const float* z   = (const float*)d_in[0];
    const float* emb = (const float*)d_in[1];
    float* out = (float*)d_out;
    char* ws = (char*)d_ws;
    unsigned short* embS = (unsigned short*)(ws + EMBS_OFF);
    unsigned short* embB = (unsigned short*)(ws + EMBB_OFF);
    float* enorm   = (float*)(ws + ENORM_OFF);
    int*   hist    = (int*)(ws + HIST_OFF);
    float* lossAcc = (float*)(ws + LOSS_OFF);
    int*   ticket  = (int*)(ws + LOSS_OFF + 4);

    prep_emb<<<32, 256, 0, stream>>>(emb, embS, embB, enorm, hist, lossAcc, ticket);
    fused_kernel<<<512, 256, 0, stream>>>(z, (const short8*)embS, embB, enorm,
                                          out, hist, lossAcc, ticket);
}